// Round 12
// baseline (157.635 us; speedup 1.0000x reference)
//
#include <hip/hip_runtime.h>
#include <math.h>

// Problem constants
#define BB   4
#define CC   128
#define HH   64
#define WW   64
#define OUTC 128
#define LW   5
#define KK   25   // LW*LW
#define NCS  8    // conv1 c-split count (atomic-reduced)
#define CPER 16   // channels per split

typedef __attribute__((ext_vector_type(8))) short short8;   // 8 bf16
typedef __attribute__((ext_vector_type(4))) float floatx4;  // MFMA acc

__device__ __forceinline__ unsigned short f32_to_bf16(float v) {
    unsigned int u = __float_as_uint(v);
    u += 0x7fffu + ((u >> 16) & 1u);          // RNE
    return (unsigned short)(u >> 16);
}

// ---------------------------------------------------------------------------
// Kernel 0 (prep): two jobs in one launch.
//  i < 16384:  w2o[o][c] = bf16( sum_{r} w2[o, c*4+r] )      (o-major)
//  else:       w1t[kcg][c][kci][j] = w1[(kcg*5+kci)][c][j]   (45 contig / c)
// ---------------------------------------------------------------------------
__global__ void prep_kernel(const float* __restrict__ w2,
                            const float* __restrict__ w1,
                            unsigned short* __restrict__ w2o,
                            float* __restrict__ w1t) {
    int i = blockIdx.x * 256 + threadIdx.x;
    if (i < 16384) {
        int o = i >> 7, c = i & 127;
        const float* p = w2 + o * (4 * CC) + c * 4;
        w2o[o * CC + c] = f32_to_bf16(p[0] + p[1] + p[2] + p[3]);
    } else if (i < 16384 + 28800) {
        int j  = i - 16384;
        int jj = j % 9;
        int r  = j / 9;
        int kci = r % 5;  r /= 5;
        int c   = r % 128;
        int kcg = r / 128;
        w1t[j] = w1[(size_t)((kcg * 5 + kci) * CC + c) * 9 + jj];
    }
}

// ---------------------------------------------------------------------------
// Kernel 1: conv1 3x3 SAME. Weights staged ONCE into LDS (3.8 KB, one
// barrier); inner-loop weight reads are same-address LDS broadcasts (~free).
// 4 px/thread: 180 FMA per c-iter vs 9 VMEM x loads -> VALU-bound.
// grid: 5(kcg) * [4(b)*4(ht)*8(cs)] = 640 blocks of 256 threads.
// Same-x blocks differ only in kcg (bid stride 128 == 0 mod 8 -> same XCD).
// atomicAdd into one zeroed slab.
// ---------------------------------------------------------------------------
__global__ __launch_bounds__(256) void conv1_kernel(
        const float* __restrict__ x,
        const float* __restrict__ w1t,
        float* __restrict__ kws) {
    __shared__ float wlds[CPER * 60];   // [c][kci][12], 3.84 KB

    int bid = blockIdx.x;
    int kcg = bid >> 7;          // 0..4
    int g   = bid & 127;
    int cs  = g & 7;
    int ht  = (g >> 3) & 3;
    int b   = g >> 5;

    int t  = threadIdx.x;
    int w4 = t & 15;
    int r  = t >> 4;
    int h  = ht * 16 + r;
    int col0 = 4 * w4;

    // stage weights: 16 c x 45 dwords contiguous in w1t, padded 45->60 in LDS
    {
        const float* wb = w1t + ((size_t)kcg * CC + cs * CPER) * 45;
        for (int i = t; i < CPER * 45; i += 256) {
            int c  = i / 45;
            int j  = i - c * 45;
            int kci = j / 9;
            int jj  = j - kci * 9;
            wlds[c * 60 + kci * 12 + jj] = wb[i];
        }
    }
    __syncthreads();

    float mt = (h > 0)        ? 1.f : 0.f;
    float mb = (h < HH - 1)   ? 1.f : 0.f;
    float ml = (col0 > 0)     ? 1.f : 0.f;
    float mr = (col0 + 4 < WW)? 1.f : 0.f;
    int y0 = (h > 0) ? h - 1 : 0;
    int y2 = (h < HH - 1) ? h + 1 : HH - 1;
    int cl = (col0 > 0) ? col0 - 1 : 0;
    int cr = (col0 + 4 < WW) ? col0 + 4 : WW - 1;

    float acc[5][4];
    #pragma unroll
    for (int k = 0; k < 5; ++k)
        { acc[k][0] = 0.f; acc[k][1] = 0.f; acc[k][2] = 0.f; acc[k][3] = 0.f; }

    const float* xb = x + ((size_t)b * CC + cs * CPER) * (HH * WW);

    #pragma unroll 2
    for (int c = 0; c < CPER; ++c) {
        const float* xc = xb + c * (HH * WW);
        const float* r0p = xc + y0 * WW;
        const float* r1p = xc + h  * WW;
        const float* r2p = xc + y2 * WW;

        float4 v0 = *(const float4*)(r0p + col0);
        float4 v1 = *(const float4*)(r1p + col0);
        float4 v2 = *(const float4*)(r2p + col0);
        float l0 = r0p[cl], l1 = r1p[cl], l2 = r2p[cl];
        float q0 = r0p[cr], q1 = r1p[cr], q2 = r2p[cr];

        v0.x *= mt; v0.y *= mt; v0.z *= mt; v0.w *= mt;
        l0 *= mt * ml; q0 *= mt * mr;
        l1 *= ml; q1 *= mr;
        v2.x *= mb; v2.y *= mb; v2.z *= mb; v2.w *= mb;
        l2 *= mb * ml; q2 *= mb * mr;

        const float* wc = &wlds[c * 60];
        #pragma unroll
        for (int kci = 0; kci < 5; ++kci) {
            const float* wk = wc + kci * 12;   // broadcast LDS reads (free)
            float w0 = wk[0], w1v = wk[1], w2v = wk[2];
            float w3 = wk[3], w4v = wk[4], w5v = wk[5];
            float w6 = wk[6], w7v = wk[7], w8v = wk[8];
            acc[kci][0] += l0   * w0 + v0.x * w1v + v0.y * w2v
                         + l1   * w3 + v1.x * w4v + v1.y * w5v
                         + l2   * w6 + v2.x * w7v + v2.y * w8v;
            acc[kci][1] += v0.x * w0 + v0.y * w1v + v0.z * w2v
                         + v1.x * w3 + v1.y * w4v + v1.z * w5v
                         + v2.x * w6 + v2.y * w7v + v2.z * w8v;
            acc[kci][2] += v0.y * w0 + v0.z * w1v + v0.w * w2v
                         + v1.y * w3 + v1.z * w4v + v1.w * w5v
                         + v2.y * w6 + v2.z * w7v + v2.w * w8v;
            acc[kci][3] += v0.z * w0 + v0.w * w1v + q0   * w2v
                         + v1.z * w3 + v1.w * w4v + q1   * w5v
                         + v2.z * w6 + v2.w * w7v + q2   * w8v;
        }
    }

    float* kb = kws + ((size_t)b * KK + kcg * 5) * (HH * WW) + h * WW + col0;
    #pragma unroll
    for (int kci = 0; kci < 5; ++kci) {
        float* p = kb + (size_t)kci * (HH * WW);
        atomicAdd(p,     acc[kci][0]);
        atomicAdd(p + 1, acc[kci][1]);
        atomicAdd(p + 2, acc[kci][2]);
        atomicAdd(p + 3, acc[kci][3]);
    }
}

// ---------------------------------------------------------------------------
// Kernel 2: fused softmax (per-thread registers) + local attention +
//           MFMA GEMM (bf16) + 2x2-replicated write.  (unchanged from R11)
// Block = 16 px (2 rows x 8 cols): grid 4(b)*32(hb)*8(wq) = 1024 blocks.
// ---------------------------------------------------------------------------
__global__ __launch_bounds__(256) void fused_kernel(
        const float* __restrict__ x,
        const unsigned short* __restrict__ w2o,
        const float* __restrict__ b1,
        const float* __restrict__ b2,
        const float* __restrict__ kws,
        float* __restrict__ out) {
    __shared__ float pk[KK * 16];                  // logits [k][px]  (1.6 KB)
    __shared__ float xld[64 * 76];                 // x tile          (19.5 KB)
    __shared__ unsigned short sKT[16 * 136];       // s bf16 [px][c]  (4.25 KB)

    int bid = blockIdx.x;
    int wq = bid & 7;
    int hb = (bid >> 3) & 31;
    int b  = bid >> 8;
    int t  = threadIdx.x;

    // ---- Phase 1: read conv1 logits (single slab) + bias ----
    for (int i = t; i < KK * 16; i += 256) {
        int kk = i >> 4, px = i & 15;
        int y  = 2 * hb + (px >> 3);
        int xc = wq * 8 + (px & 7);
        pk[i] = kws[((size_t)b * KK + kk) * (HH * WW) + y * WW + xc] + b1[kk];
    }
    __syncthreads();

    // ---- per-thread softmax for px pair {2pp, 2pp+1} (same row) ----
    int pp = t & 7, cl = t >> 3;   // cl in 0..31 (c-lane)
    int px0 = 2 * pp;
    float p0[KK], p1[KK];
    #pragma unroll
    for (int k = 0; k < KK; ++k) {
        float2 l = *(const float2*)&pk[k * 16 + px0];
        p0[k] = l.x; p1[k] = l.y;
    }
    float mx0 = -1e30f, mx1 = -1e30f;
    #pragma unroll
    for (int k = 0; k < KK; ++k) {
        mx0 = fmaxf(mx0, p0[k]); mx1 = fmaxf(mx1, p1[k]);
    }
    float s0 = 0.f, s1 = 0.f;
    #pragma unroll
    for (int k = 0; k < KK; ++k) {
        p0[k] = __expf(p0[k] - mx0); s0 += p0[k];
        p1[k] = __expf(p1[k] - mx1); s1 += p1[k];
    }
    float i0 = 1.f / s0, i1 = 1.f / s1;
    #pragma unroll
    for (int k = 0; k < KK; ++k) { p0[k] *= i0; p1[k] *= i1; }

    int prow = px0 >> 3, pcol = px0 & 7;

    // ---- Phase 2: s[c][px] over 2 chunks of 64 channels ----
    const float* xb = x + (size_t)(b * CC) * (HH * WW);
    for (int ch = 0; ch < 2; ++ch) {
        __syncthreads();
        for (int i = t; i < 2304; i += 256) {
            int c   = i / 36;
            int rem = i - c * 36;
            int di  = rem / 6;
            int c2  = rem - di * 6;
            int y   = 2 * hb - 2 + di;
            int x0  = wq * 8 + 2 * c2 - 2;
            float2 v = make_float2(0.f, 0.f);
            if (y >= 0 && y < HH && x0 >= 0 && x0 <= WW - 2)
                v = *(const float2*)(xb + (size_t)(ch * 64 + c) * (HH * WW)
                                     + y * WW + x0);
            *(float2*)&xld[c * 76 + di * 12 + 2 * c2] = v;
        }
        __syncthreads();

        #pragma unroll
        for (int j = 0; j < 2; ++j) {          // 2 channels per thread
            int c = cl * 2 + j;
            float a0 = 0.f, a1 = 0.f;
            const float* xr = &xld[c * 76 + prow * 12 + pcol];
            #pragma unroll
            for (int di = 0; di < 5; ++di) {
                float2 x01 = *(const float2*)(xr + di * 12);
                float2 x23 = *(const float2*)(xr + di * 12 + 2);
                float2 x45 = *(const float2*)(xr + di * 12 + 4);
                a0 += p0[di*5+0] * x01.x + p0[di*5+1] * x01.y + p0[di*5+2] * x23.x
                    + p0[di*5+3] * x23.y + p0[di*5+4] * x45.x;
                a1 += p1[di*5+0] * x01.y + p1[di*5+1] * x23.x + p1[di*5+2] * x23.y
                    + p1[di*5+3] * x45.x + p1[di*5+4] * x45.y;
            }
            int cg = ch * 64 + c;
            sKT[px0 * 136 + cg]       = f32_to_bf16(a0);
            sKT[(px0 + 1) * 136 + cg] = f32_to_bf16(a1);
        }
    }
    __syncthreads();

    // ---- Phase 3: MFMA. C[o][px] = sum_c W2s[o][c] * s[c][px] ----
    int lane = t & 63;
    int wv   = t >> 6;
    int fpx  = lane & 15;
    int quad = lane >> 4;

    floatx4 acc0 = {0.f, 0.f, 0.f, 0.f};
    floatx4 acc1 = {0.f, 0.f, 0.f, 0.f};
    #pragma unroll
    for (int ks = 0; ks < 4; ++ks) {
        short8 bfrag = *(const short8*)&sKT[fpx * 136 + ks * 32 + quad * 8];
        short8 a0f = *(const short8*)&w2o[(size_t)(wv * 32 + fpx) * CC
                                          + ks * 32 + quad * 8];
        short8 a1f = *(const short8*)&w2o[(size_t)(wv * 32 + 16 + fpx) * CC
                                          + ks * 32 + quad * 8];
        acc0 = __builtin_amdgcn_mfma_f32_16x16x32_bf16(a0f, bfrag, acc0, 0, 0, 0);
        acc1 = __builtin_amdgcn_mfma_f32_16x16x32_bf16(a1f, bfrag, acc1, 0, 0, 0);
    }

    // ---- epilogue: 2x2-replicated float2 writes ----
    float* ob = out + (size_t)(b * OUTC) * (4 * HH * WW);
    int y0r  = 2 * (2 * hb + (fpx >> 3));
    int xcol = 2 * (wq * 8 + (fpx & 7));
    #pragma unroll
    for (int tile = 0; tile < 2; ++tile) {
        float4 bv = *(const float4*)(b2 + wv * 32 + tile * 16 + quad * 4);
        #pragma unroll
        for (int reg = 0; reg < 4; ++reg) {
            int o = wv * 32 + tile * 16 + quad * 4 + reg;
            float v = (tile ? acc1[reg] : acc0[reg])
                    + ((const float*)&bv)[reg];
            float2 v2 = make_float2(v, v);
            float* r0 = ob + ((size_t)o * (2 * HH) + y0r) * (2 * WW) + xcol;
            *(float2*)(r0)          = v2;
            *(float2*)(r0 + 2 * WW) = v2;
        }
    }
}

// ---------------------------------------------------------------------------
extern "C" void kernel_launch(void* const* d_in, const int* in_sizes, int n_in,
                              void* d_out, int out_size, void* d_ws, size_t ws_size,
                              hipStream_t stream) {
    const float* x  = (const float*)d_in[0];
    const float* w1 = (const float*)d_in[1];
    const float* b1 = (const float*)d_in[2];
    const float* w2 = (const float*)d_in[3];
    const float* b2 = (const float*)d_in[4];
    float* out = (float*)d_out;

    const size_t slab = (size_t)BB * KK * HH * WW;        // 409600 floats
    float* kws = (float*)d_ws;                            // 1.6 MB (atomic)
    unsigned short* w2o = (unsigned short*)(kws + slab);  // 32 KB
    float* w1t = (float*)(w2o + (size_t)OUTC * CC);       // 115 KB

    hipMemsetAsync(kws, 0, slab * sizeof(float), stream);
    prep_kernel<<<(16384 + 28800 + 255) / 256, 256, 0, stream>>>(w2, w1, w2o, w1t);
    conv1_kernel<<<5 * 128, 256, 0, stream>>>(x, w1t, kws);
    fused_kernel<<<BB * 32 * 8, 256, 0, stream>>>(x, w2o, b1, b2, kws, out);
}